// Round 3
// baseline (5460.543 us; speedup 1.0000x reference)
//
#include <hip/hip_runtime.h>
#include <stdint.h>
#include <stddef.h>

#define S_LEN 2048
#define BATCH 32
#define NIN   256
#define NH    256
#define NG    768   // 3*NH

typedef _Float16 half2_t __attribute__((ext_vector_type(2)));
typedef _Float16 half8_t __attribute__((ext_vector_type(8)));
typedef int      int16v  __attribute__((ext_vector_type(16)));
typedef _Float16 f16x8   __attribute__((ext_vector_type(8)));
typedef _Float16 f16x4   __attribute__((ext_vector_type(4)));
typedef float    f32x4   __attribute__((ext_vector_type(4)));

#if __has_builtin(__builtin_amdgcn_exp2f)
#define EXP2F(x) __builtin_amdgcn_exp2f(x)
#else
#define EXP2F(x) exp2f(x)
#endif

static __device__ __forceinline__ float fdot2(half2_t a, half2_t b, float c) {
  return __builtin_amdgcn_fdot2(a, b, c, false);
}
static __device__ __forceinline__ half2_t pack2(float lo, float hi) {
  half2_t r; r[0] = (_Float16)lo; r[1] = (_Float16)hi; return r;
}
static __device__ __forceinline__ float sigmoid_fast(float x) {
  float e = EXP2F(-1.44269504088896340736f * x);
  return 1.0f / (1.0f + e);
}
static __device__ __forceinline__ float tanh_fast(float x) {
  float e = EXP2F(2.88539008177792681472f * x);
  return 1.0f - 2.0f / (1.0f + e);
}
static __device__ __forceinline__ f32x4 MFMA16(f16x8 a, f16x8 b, f32x4 c) {
  return __builtin_amdgcn_mfma_f32_16x16x32_f16(a, b, c, 0, 0, 0);
}

// bit-cast helpers (xproj path)
#define BH(x)    __builtin_bit_cast(half2_t, (x))
#define BW(W, e) __builtin_bit_cast(half2_t, (int)((W)[e]))

#define DOT16(W, i0) do {                                                     \
    int4 q0 = hls[(i0) + 0], q1 = hls[(i0) + 1];                              \
    int4 q2 = hls[(i0) + 2], q3 = hls[(i0) + 3];                              \
    a0 = fdot2(BH(q0.x), BW(W, 0),  a0); a1 = fdot2(BH(q0.y), BW(W, 1),  a1);\
    a2 = fdot2(BH(q0.z), BW(W, 2),  a2); a3 = fdot2(BH(q0.w), BW(W, 3),  a3);\
    a0 = fdot2(BH(q1.x), BW(W, 4),  a0); a1 = fdot2(BH(q1.y), BW(W, 5),  a1);\
    a2 = fdot2(BH(q1.z), BW(W, 6),  a2); a3 = fdot2(BH(q1.w), BW(W, 7),  a3);\
    a0 = fdot2(BH(q2.x), BW(W, 8),  a0); a1 = fdot2(BH(q2.y), BW(W, 9),  a1);\
    a2 = fdot2(BH(q2.z), BW(W, 10), a2); a3 = fdot2(BH(q2.w), BW(W, 11), a3);\
    a0 = fdot2(BH(q3.x), BW(W, 12), a0); a1 = fdot2(BH(q3.y), BW(W, 13), a1);\
    a2 = fdot2(BH(q3.z), BW(W, 14), a2); a3 = fdot2(BH(q3.w), BW(W, 15), a3);\
  } while (0)

#define LDW(W, o) do {                                                        \
    int4 q0 = wsrc[(o) + 0], q1 = wsrc[(o) + 1];                              \
    int4 q2 = wsrc[(o) + 2], q3 = wsrc[(o) + 3];                              \
    W = (int16v){q0.x, q0.y, q0.z, q0.w, q1.x, q1.y, q1.z, q1.w,              \
                 q2.x, q2.y, q2.z, q2.w, q3.x, q3.y, q3.z, q3.w};             \
  } while (0)

// ---------------- prep: input f32 -> f16 ----------------
__global__ __launch_bounds__(256) void prep_in_kernel(const float* __restrict__ in,
                                                      _Float16* __restrict__ in16) {
  size_t v = (size_t)blockIdx.x * 256 + threadIdx.x;
  const float4* p4 = (const float4*)in;
  float4 a = p4[v * 2 + 0];
  float4 b = p4[v * 2 + 1];
  half8_t o;
  o[0] = (_Float16)a.x; o[1] = (_Float16)a.y; o[2] = (_Float16)a.z; o[3] = (_Float16)a.w;
  o[4] = (_Float16)b.x; o[5] = (_Float16)b.y; o[6] = (_Float16)b.z; o[7] = (_Float16)b.w;
  ((half8_t*)in16)[v] = o;
}

// ---------------- prep: weights ----------------
// whh4: MFMA A-fragments for the recurrence. Frag index F = w*3072 +
// ((u*3+gate)*8+kt)*64 + lane; dword v of frag = half2 of
// W_hh[row = gate*256 + 32w + 16u + (lane&15)][col = 32kt + 8*(lane>>4) + 2v].
// Flat dword index == ((F*4)+v) == the idx below (identity mapping).
__global__ __launch_bounds__(256) void prep_w_kernel(const float* __restrict__ W_ih,
                                                     const float* __restrict__ W_hh,
                                                     const float* __restrict__ b_ih,
                                                     const float* __restrict__ b_hh,
                                                     half2_t* __restrict__ whh4,
                                                     half2_t* __restrict__ wih2,
                                                     float* __restrict__ bias) {
  int idx = blockIdx.x * 256 + threadIdx.x;
  if (idx < 128 * NG) {                       // 98304 dwords = 384 KiB
    int v  = idx & 3;
    int l  = (idx >> 2) & 63;
    int kt = (idx >> 8) & 7;
    int r1 = idx >> 11;                       // (w*2+u)*3 + gate, 0..47
    int gate = r1 % 3;
    int r2 = r1 / 3;
    int u  = r2 & 1;
    int ww = r2 >> 1;
    int row = gate * NH + 32 * ww + 16 * u + (l & 15);
    int col = 32 * kt + 8 * (l >> 4) + 2 * v;
    whh4[idx] = pack2(W_hh[(size_t)row * NH + col], W_hh[(size_t)row * NH + col + 1]);
  } else if (idx < 2 * 128 * NG) {
    int i2 = idx - 128 * NG;
    int g = i2 >> 7, kk = i2 & 127;
    wih2[(size_t)g * 128 + kk] = pack2(W_ih[(size_t)g * NIN + 2 * kk], W_ih[(size_t)g * NIN + 2 * kk + 1]);
  } else if (idx < 2 * 128 * NG + NG) {
    int g = idx - 2 * 128 * NG;
    bias[g] = b_ih[g] + b_hh[g];
  }
}

// ---------------- x_proj GEMM (unchanged) ----------------
__global__
__attribute__((amdgpu_flat_work_group_size(768, 768), amdgpu_waves_per_eu(3, 3)))
void xproj_kernel(const _Float16* __restrict__ in16,
                  const half2_t* __restrict__ wih2,
                  const float* __restrict__ bias,
                  float* __restrict__ xp_out) {
  __shared__ char occ_pad[86016];
  {
    unsigned lp = (unsigned)(uintptr_t)&occ_pad[0];
    asm volatile("" :: "v"(lp));
  }
  const int g = threadIdx.x;
  const int row0 = blockIdx.x * 64;
  const float bg = bias[g];

  int16v w0, w1, w2, w3, w4, w5, w6, w7;
  {
    const int4* wsrc = (const int4*)(wih2 + (size_t)g * 128);
    LDW(w0, 0);  LDW(w1, 4);  LDW(w2, 8);  LDW(w3, 12);
    LDW(w4, 16); LDW(w5, 20); LDW(w6, 24); LDW(w7, 28);
  }

  for (int r = 0; r < 64; ++r) {
    const int row = row0 + r;
    const int4* hls = (const int4*)(in16 + (size_t)row * NIN);
    float a0 = 0.f, a1 = 0.f, a2 = 0.f, a3 = 0.f;
    DOT16(w0, 0);  DOT16(w1, 4);  DOT16(w2, 8);  DOT16(w3, 12);
    DOT16(w4, 16); DOT16(w5, 20); DOT16(w6, 24); DOT16(w7, 28);
    xp_out[(size_t)row * NG + g] = (a0 + a1) + (a2 + a3) + bg;
  }
}

// ---------------- recurrence: MFMA, 16 chains/block, 2 blocks ----------------
// R10: R8/R9 falsified exchange/sync as the floor -- the per-chain VALU+LDS dot
// engine is. MFMA computes all 16 batch-chains' matvec in ~480 cyc/SIMD/step:
// 8 waves (512 thr, 2/SIMD, 256-VGPR cap). Wave w owns gate-rows
// {32w..32w+31} of r,z,n (6 16x16 tiles), K=256 = 8 k-tiles -> 48 MFMA/wave.
// C-layout (col=lane&15=batch, row=4*(lane>>4)+reg): lane holds r,z,n for the
// SAME (j,b) in its 3 accumulators -> elementwise fully in-register, no mv
// exchange. acc-init = xp (C-in is free adder); next-step xp loaded into the
// dead acc regs at tail (latency hidden across barrier). h round-trip: 17 KB
// double-buffered LDS [b][264-pad j] f16: write 2 x b64/lane, B-frags read
// 8 x b128/lane (2-way bank, free). ONE raw lgkmcnt+s_barrier per step.
__global__
__attribute__((amdgpu_flat_work_group_size(512, 512), amdgpu_waves_per_eu(2, 2)))
void gru_kernel(const float* __restrict__ xp,
                const f16x8* __restrict__ whh4,
                float* __restrict__ out) {
  const int blk = blockIdx.x;       // batch half: batches [16*blk, 16*blk+16)
  const int tid = threadIdx.x;
  const int w   = tid >> 6;
  const int l   = tid & 63;
  const int lb  = l & 15;           // batch-offset / A-row / B-col
  const int lq  = l >> 4;           // k-quarter / C-row-quarter
  const int jb  = 32 * w;           // wave's row base within a gate

  f16x8 W[2][3][8];                 // 48 frags = 192 VGPR (constant-indexed)
  {
    const f16x8* wp = whh4 + (size_t)w * 3072 + l;
#pragma unroll
    for (int u = 0; u < 2; ++u)
#pragma unroll
      for (int gt = 0; gt < 3; ++gt)
#pragma unroll
        for (int kt = 0; kt < 8; ++kt)
          W[u][gt][kt] = wp[(size_t)(((u * 3 + gt) * 8) + kt) * 64];
  }

  __shared__ _Float16 hbuf[2][16][264];   // [buf][b][j padded] : 16.9 KB
  for (int i = tid; i < 16 * 264; i += 512) ((_Float16*)hbuf)[i] = (_Float16)0.f;

  const float* xpl = xp  + ((size_t)blk * 16 + lb) * NG + jb + 4 * lq;
  float*       opl = out + ((size_t)blk * 16 + lb) * NH + jb + 4 * lq;

  // acc-init for t=0 comes straight from xp (C-in of the MFMA chain)
  f32x4 accR0 = *(const f32x4*)(xpl + 0 * NH +  0);
  f32x4 accR1 = *(const f32x4*)(xpl + 0 * NH + 16);
  f32x4 accZ0 = *(const f32x4*)(xpl + 1 * NH +  0);
  f32x4 accZ1 = *(const f32x4*)(xpl + 1 * NH + 16);
  f32x4 xn0   = *(const f32x4*)(xpl + 2 * NH +  0);
  f32x4 xn1   = *(const f32x4*)(xpl + 2 * NH + 16);
  f32x4 accN0, accN1;

  float ho[2][4];
#pragma unroll
  for (int u = 0; u < 2; ++u)
#pragma unroll
    for (int q = 0; q < 4; ++q) ho[u][q] = 0.f;

  __syncthreads();   // buf0 zeroed

  for (int t = 0; t < S_LEN; ++t) {
    const _Float16* hb = &hbuf[t & 1][0][0];
    accN0 = (f32x4){0.f, 0.f, 0.f, 0.f};
    accN1 = (f32x4){0.f, 0.f, 0.f, 0.f};

    // B-fragments: lane reads h[32kt+8lq .. +7][b=lb], double-buffered
    f16x8 Ba = *(const f16x8*)(hb + lb * 264 + 8 * lq);
#pragma unroll
    for (int kt = 0; kt < 8; ++kt) {
      f16x8 Bn = Ba;
      if (kt < 7) Bn = *(const f16x8*)(hb + lb * 264 + 32 * (kt + 1) + 8 * lq);
      accN0 = MFMA16(W[0][2][kt], Ba, accN0);   // N first: no xp dependence
      accN1 = MFMA16(W[1][2][kt], Ba, accN1);
      accR0 = MFMA16(W[0][0][kt], Ba, accR0);
      accR1 = MFMA16(W[1][0][kt], Ba, accR1);
      accZ0 = MFMA16(W[0][1][kt], Ba, accZ0);
      accZ1 = MFMA16(W[1][1][kt], Ba, accZ1);
      Ba = Bn;
    }

    // elementwise: lane owns (j = jb + 16u + 4lq + q, b = 16blk + lb)
#define ELEM(AR, AZ, AN, XN, U) do {                                   \
      _Pragma("unroll")                                                \
      for (int q = 0; q < 4; ++q) {                                    \
        float r = sigmoid_fast(AR[q]);                                 \
        float z = sigmoid_fast(AZ[q]);                                 \
        float mvn = AN[q];                                             \
        float n = tanh_fast(XN[q] + mvn + r * mvn);  /* torch quirk */ \
        ho[U][q] = z * (ho[U][q] - n) + n;                             \
      }                                                                \
    } while (0)
    ELEM(accR0, accZ0, accN0, xn0, 0);
    ELEM(accR1, accZ1, accN1, xn1, 1);
#undef ELEM

    // output stores (2 x b128, fire-and-forget)
    float* os = opl + (size_t)t * BATCH * NH;
    *(f32x4*)(os +  0) = (f32x4){ho[0][0], ho[0][1], ho[0][2], ho[0][3]};
    *(f32x4*)(os + 16) = (f32x4){ho[1][0], ho[1][1], ho[1][2], ho[1][3]};

    // h -> other LDS buffer (2 x b64)
    _Float16* hw = &hbuf[(t + 1) & 1][0][0] + lb * 264 + jb + 4 * lq;
    *(f16x4*)(hw +  0) = (f16x4){(_Float16)ho[0][0], (_Float16)ho[0][1],
                                 (_Float16)ho[0][2], (_Float16)ho[0][3]};
    *(f16x4*)(hw + 16) = (f16x4){(_Float16)ho[1][0], (_Float16)ho[1][1],
                                 (_Float16)ho[1][2], (_Float16)ho[1][3]};

    // next step's xp into the now-dead acc regs (hidden across barrier;
    // t=2047 overruns into in16 region: valid, unused)
    const float* xnp = xpl + (size_t)(t + 1) * BATCH * NG;
    accR0 = *(const f32x4*)(xnp + 0 * NH +  0);
    accR1 = *(const f32x4*)(xnp + 0 * NH + 16);
    accZ0 = *(const f32x4*)(xnp + 1 * NH +  0);
    accZ1 = *(const f32x4*)(xnp + 1 * NH + 16);
    xn0   = *(const f32x4*)(xnp + 2 * NH +  0);
    xn1   = *(const f32x4*)(xnp + 2 * NH + 16);

    // h ds_writes visible to all waves; NO vmcnt drain (stores/loads in flight)
    asm volatile("s_waitcnt lgkmcnt(0)\n\ts_barrier" ::: "memory");
  }

  float* fs = out + (size_t)S_LEN * BATCH * NH + ((size_t)blk * 16 + lb) * NH + jb + 4 * lq;
  *(f32x4*)(fs +  0) = (f32x4){ho[0][0], ho[0][1], ho[0][2], ho[0][3]};
  *(f32x4*)(fs + 16) = (f32x4){ho[1][0], ho[1][1], ho[1][2], ho[1][3]};
}

extern "C" void kernel_launch(void* const* d_in, const int* in_sizes, int n_in,
                              void* d_out, int out_size, void* d_ws, size_t ws_size,
                              hipStream_t stream) {
  const float* input = (const float*)d_in[0];
  const float* W_ih  = (const float*)d_in[1];
  const float* W_hh  = (const float*)d_in[2];
  const float* b_ih  = (const float*)d_in[3];
  const float* b_hh  = (const float*)d_in[4];
  float* out = (float*)d_out;

  const size_t SB = (size_t)S_LEN * BATCH;           // 65536
  const size_t xp_b   = SB * NG * 4;                 // 192 MiB
  const size_t in16_b = SB * NIN * 2;                // 32 MiB
  const size_t w_b    = (size_t)128 * NG * 4;        // 384 KiB each

  char* p = (char*)d_ws;
  float*    xp    = (float*)p;                p += xp_b;
  _Float16* in16  = (_Float16*)p;             p += in16_b;
  half2_t*  whh4  = (half2_t*)p;              p += w_b;
  half2_t*  wih2  = (half2_t*)p;              p += w_b;
  float*    bias  = (float*)p;

  prep_in_kernel<<<8192, 256, 0, stream>>>(input, in16);
  prep_w_kernel<<<(2 * 128 * NG + NG + 255) / 256, 256, 0, stream>>>(W_ih, W_hh, b_ih, b_hh,
                                                                     whh4, wih2, bias);
  xproj_kernel<<<1024, 768, 0, stream>>>(in16, wih2, bias, xp);
  gru_kernel<<<2, 512, 0, stream>>>(xp, (const f16x8*)whh4, out);
  (void)out_size; (void)n_in; (void)in_sizes; (void)ws_size;
}

// Round 4
// 2620.666 us; speedup vs baseline: 2.0836x; 2.0836x over previous
//
#include <hip/hip_runtime.h>
#include <stdint.h>
#include <stddef.h>

#define S_LEN 2048
#define BATCH 32
#define NIN   256
#define NH    256
#define NG    768   // 3*NH

typedef _Float16 half2_t __attribute__((ext_vector_type(2)));
typedef _Float16 half8_t __attribute__((ext_vector_type(8)));
typedef int      int16v  __attribute__((ext_vector_type(16)));

#if __has_builtin(__builtin_amdgcn_exp2f)
#define EXP2F(x) __builtin_amdgcn_exp2f(x)
#else
#define EXP2F(x) exp2f(x)
#endif

static __device__ __forceinline__ float fdot2(half2_t a, half2_t b, float c) {
  return __builtin_amdgcn_fdot2(a, b, c, false);
}
static __device__ __forceinline__ half2_t pack2(float lo, float hi) {
  half2_t r; r[0] = (_Float16)lo; r[1] = (_Float16)hi; return r;
}
static __device__ __forceinline__ float sigmoid_fast(float x) {
  float e = EXP2F(-1.44269504088896340736f * x);
  return 1.0f / (1.0f + e);
}
static __device__ __forceinline__ float tanh_fast(float x) {
  float e = EXP2F(2.88539008177792681472f * x);
  return 1.0f - 2.0f / (1.0f + e);
}

// quad reduction via DPP quad_perm (register-file exchange, no LDS, no
// barrier): xor1 then xor2 -> all 4 lanes hold the full 4-way sum,
// bit-identical.
static __device__ __forceinline__ float quad_sum(float v) {
  int y1 = __builtin_amdgcn_mov_dpp(__builtin_bit_cast(int, v), 0xB1, 0xF, 0xF, true);
  float s = v + __builtin_bit_cast(float, y1);
  int y2 = __builtin_amdgcn_mov_dpp(__builtin_bit_cast(int, s), 0x4E, 0xF, 0xF, true);
  return s + __builtin_bit_cast(float, y2);
}

// bit-cast helpers: element extracts use LITERAL indices -> pure SSA
#define BH(x)    __builtin_bit_cast(half2_t, (x))
#define BW(W, e) __builtin_bit_cast(half2_t, (int)((W)[e]))

// ---- xproj path ----
#define DOT16(W, i0) do {                                                     \
    int4 q0 = hls[(i0) + 0], q1 = hls[(i0) + 1];                              \
    int4 q2 = hls[(i0) + 2], q3 = hls[(i0) + 3];                              \
    a0 = fdot2(BH(q0.x), BW(W, 0),  a0); a1 = fdot2(BH(q0.y), BW(W, 1),  a1);\
    a2 = fdot2(BH(q0.z), BW(W, 2),  a2); a3 = fdot2(BH(q0.w), BW(W, 3),  a3);\
    a0 = fdot2(BH(q1.x), BW(W, 4),  a0); a1 = fdot2(BH(q1.y), BW(W, 5),  a1);\
    a2 = fdot2(BH(q1.z), BW(W, 6),  a2); a3 = fdot2(BH(q1.w), BW(W, 7),  a3);\
    a0 = fdot2(BH(q2.x), BW(W, 8),  a0); a1 = fdot2(BH(q2.y), BW(W, 9),  a1);\
    a2 = fdot2(BH(q2.z), BW(W, 10), a2); a3 = fdot2(BH(q2.w), BW(W, 11), a3);\
    a0 = fdot2(BH(q3.x), BW(W, 12), a0); a1 = fdot2(BH(q3.y), BW(W, 13), a1);\
    a2 = fdot2(BH(q3.z), BW(W, 14), a2); a3 = fdot2(BH(q3.w), BW(W, 15), a3);\
  } while (0)

// ---- gru path: one 16B h chunk (4 half2) against 6 row-slices (2j x 3 gates).
// Accumulator reuse distance = 6 instructions -> no VALU dep stalls.
#define DOT6(q, U0, U1, U2, U3, U4, U5, o) do {                               \
    a0 = fdot2(BH(q.x), BW(U0,(o)+0), a0); a1 = fdot2(BH(q.x), BW(U1,(o)+0), a1);\
    a2 = fdot2(BH(q.x), BW(U2,(o)+0), a2); a3 = fdot2(BH(q.x), BW(U3,(o)+0), a3);\
    a4 = fdot2(BH(q.x), BW(U4,(o)+0), a4); a5 = fdot2(BH(q.x), BW(U5,(o)+0), a5);\
    a0 = fdot2(BH(q.y), BW(U0,(o)+1), a0); a1 = fdot2(BH(q.y), BW(U1,(o)+1), a1);\
    a2 = fdot2(BH(q.y), BW(U2,(o)+1), a2); a3 = fdot2(BH(q.y), BW(U3,(o)+1), a3);\
    a4 = fdot2(BH(q.y), BW(U4,(o)+1), a4); a5 = fdot2(BH(q.y), BW(U5,(o)+1), a5);\
    a0 = fdot2(BH(q.z), BW(U0,(o)+2), a0); a1 = fdot2(BH(q.z), BW(U1,(o)+2), a1);\
    a2 = fdot2(BH(q.z), BW(U2,(o)+2), a2); a3 = fdot2(BH(q.z), BW(U3,(o)+2), a3);\
    a4 = fdot2(BH(q.z), BW(U4,(o)+2), a4); a5 = fdot2(BH(q.z), BW(U5,(o)+2), a5);\
    a0 = fdot2(BH(q.w), BW(U0,(o)+3), a0); a1 = fdot2(BH(q.w), BW(U1,(o)+3), a1);\
    a2 = fdot2(BH(q.w), BW(U2,(o)+3), a2); a3 = fdot2(BH(q.w), BW(U3,(o)+3), a3);\
    a4 = fdot2(BH(q.w), BW(U4,(o)+3), a4); a5 = fdot2(BH(q.w), BW(U5,(o)+3), a5);\
  } while (0)

#define LDW(W, o) do {                                                        \
    int4 q0 = wsrc[(o) + 0], q1 = wsrc[(o) + 1];                              \
    int4 q2 = wsrc[(o) + 2], q3 = wsrc[(o) + 3];                              \
    W = (int16v){q0.x, q0.y, q0.z, q0.w, q1.x, q1.y, q1.z, q1.w,              \
                 q2.x, q2.y, q2.z, q2.w, q3.x, q3.y, q3.z, q3.w};             \
  } while (0)

// ---------------- prep: input f32 -> f16 ----------------
__global__ __launch_bounds__(256) void prep_in_kernel(const float* __restrict__ in,
                                                      _Float16* __restrict__ in16) {
  size_t v = (size_t)blockIdx.x * 256 + threadIdx.x;
  const float4* p4 = (const float4*)in;
  float4 a = p4[v * 2 + 0];
  float4 b = p4[v * 2 + 1];
  half8_t o;
  o[0] = (_Float16)a.x; o[1] = (_Float16)a.y; o[2] = (_Float16)a.z; o[3] = (_Float16)a.w;
  o[4] = (_Float16)b.x; o[5] = (_Float16)b.y; o[6] = (_Float16)b.z; o[7] = (_Float16)b.w;
  ((half8_t*)in16)[v] = o;
}

// ---------------- prep: weights ----------------
// whh3 layout (R11, G=6/S=4): thread tid = j1*4+c owns 192 contiguous dwords
// [d][kk], d = gate*2+jj in 0..5, kk in 0..31: half2 of
// W_hh[row = gate*256 + 2*j1 + jj][col = 64*c + 2*kk .. +1].
__global__ __launch_bounds__(256) void prep_w_kernel(const float* __restrict__ W_ih,
                                                     const float* __restrict__ W_hh,
                                                     const float* __restrict__ b_ih,
                                                     const float* __restrict__ b_hh,
                                                     half2_t* __restrict__ whh3,
                                                     half2_t* __restrict__ wih2,
                                                     float* __restrict__ bias) {
  int idx = blockIdx.x * 256 + threadIdx.x;
  if (idx < 128 * NG) {                      // 98304 dwords = 384 KiB
    int tid = idx / 192;
    int r   = idx - tid * 192;
    int d   = r >> 5, kk = r & 31;
    int gate = d >> 1, jj = d & 1;
    int c  = tid & 3, j1 = tid >> 2;
    int row = gate * NH + 2 * j1 + jj;
    int col = 64 * c + 2 * kk;
    whh3[idx] = pack2(W_hh[(size_t)row * NH + col], W_hh[(size_t)row * NH + col + 1]);
  } else if (idx < 2 * 128 * NG) {
    int i2 = idx - 128 * NG;
    int g = i2 >> 7, kk = i2 & 127;
    wih2[(size_t)g * 128 + kk] = pack2(W_ih[(size_t)g * NIN + 2 * kk], W_ih[(size_t)g * NIN + 2 * kk + 1]);
  } else if (idx < 2 * 128 * NG + NG) {
    int g = idx - 2 * 128 * NG;
    bias[g] = b_ih[g] + b_hh[g];
  }
}

// ---------------- x_proj GEMM (weight-pin added) ----------------
__global__
__attribute__((amdgpu_flat_work_group_size(768, 768), amdgpu_waves_per_eu(3, 3)))
void xproj_kernel(const _Float16* __restrict__ in16,
                  const half2_t* __restrict__ wih2,
                  const float* __restrict__ bias,
                  float* __restrict__ xp_out) {
  __shared__ char occ_pad[86016];
  {
    unsigned lp = (unsigned)(uintptr_t)&occ_pad[0];
    asm volatile("" :: "v"(lp));
  }
  const int g = threadIdx.x;
  const int row0 = blockIdx.x * 64;
  const float bg = bias[g];

  int16v w0, w1, w2, w3, w4, w5, w6, w7;
  {
    const int4* wsrc = (const int4*)(wih2 + (size_t)g * 128);
    LDW(w0, 0);  LDW(w1, 4);  LDW(w2, 8);  LDW(w3, 12);
    LDW(w4, 16); LDW(w5, 20); LDW(w6, 24); LDW(w7, 28);
  }
  // pin: values become asm-opaque -> loads can't be re-materialized in-loop
  asm volatile("" : "+v"(w0), "+v"(w1), "+v"(w2), "+v"(w3),
                    "+v"(w4), "+v"(w5), "+v"(w6), "+v"(w7));

  for (int r = 0; r < 64; ++r) {
    const int row = row0 + r;
    const int4* hls = (const int4*)(in16 + (size_t)row * NIN);
    float a0 = 0.f, a1 = 0.f, a2 = 0.f, a3 = 0.f;
    DOT16(w0, 0);  DOT16(w1, 4);  DOT16(w2, 8);  DOT16(w3, 12);
    DOT16(w4, 16); DOT16(w5, 20); DOT16(w6, 24); DOT16(w7, 28);
    xp_out[(size_t)row * NG + g] = (a0 + a1) + (a2 + a3) + bg;
  }
}

// ---------------- recurrence: G=6/S=4 K-split + pinned weights ----------------
// R11. R10 (MFMA) falsified matrix-pipe routing: 16x16x32 is 19.4 cyc/SIMD ->
// 1862 cyc/step at 16 chains/CU, worse than the 768-cyc fdot2 issue floor at
// 1 chain/CU. R9 post-mortem: VGPR_Count=116 < 192 weight dwords => compiler
// re-materialized weight loads in-loop (L2 traffic ~870 cyc/step) on top of
// 131 KB/step LDS broadcast. Fixes here: (1) asm "+v" pin keeps all 192
// weight dwords register-resident; (2) thread = (j1 = tid>>2, c = tid&3)
// computes 6 rows (2j x 3 gates) over a K-quarter -> LDS traffic halves to
// 65.5 KB/step (64 broadcast b128/CU, hidden under VALU); cross-c reduce is
// 2 DPP quad_perm butterflies (no LDS, no barrier). One raw
// lgkmcnt(0)+s_barrier per step; h double-buffered; 144B chunk stride makes
// the quad's 4 read addresses bank-disjoint.
__global__
__attribute__((amdgpu_flat_work_group_size(512, 512), amdgpu_waves_per_eu(2, 2)))
void gru_kernel(const float* __restrict__ xp,
                const half2_t* __restrict__ whh3,
                float* __restrict__ out) {
  const int b   = blockIdx.x;
  const int tid = threadIdx.x;
  const int c   = tid & 3;        // K-quarter
  const int j1  = tid >> 2;       // j-pair index 0..127
  const int jj  = c & 1;          // owned j parity
  const int jmine = 2 * j1 + jj;  // this lane's h row (lanes c, c+2 redundant)

  int16v W0a, W0b, W1a, W1b, W2a, W2b, W3a, W3b, W4a, W4b, W5a, W5b;
  {
    const int4* wsrc = (const int4*)(whh3 + (size_t)tid * 192);
    LDW(W0a, 0);  LDW(W0b, 4);  LDW(W1a, 8);  LDW(W1b, 12);
    LDW(W2a, 16); LDW(W2b, 20); LDW(W3a, 24); LDW(W3b, 28);
    LDW(W4a, 32); LDW(W4b, 36); LDW(W5a, 40); LDW(W5b, 44);
  }
  asm volatile("" : "+v"(W0a), "+v"(W0b), "+v"(W1a), "+v"(W1b),
                    "+v"(W2a), "+v"(W2b), "+v"(W3a), "+v"(W3b),
                    "+v"(W4a), "+v"(W4b), "+v"(W5a), "+v"(W5b));

  // 2 buffers x 4 chunks x 144 B (chunk = 64 f16 + 16 B pad) = 1152 B
  __shared__ __attribute__((aligned(16))) char smh[1152];
  if (tid < 288) ((int*)smh)[tid] = 0;

  const float* xq = xp + (size_t)b * NG + jmine;
  float xr_c = xq[0], xz_c = xq[NH], xn_c = xq[2 * NH];
  xq += (size_t)BATCH * NG;
  float* op = out + (size_t)b * NH + jmine;

  const int wofs = 144 * (jmine >> 6) + 2 * (jmine & 63);  // h write offset

  float h = 0.f;
  __syncthreads();

  for (int t = 0; t < S_LEN; ++t) {
    // prefetch xp row t+1 (t=2047 overruns into in16 region: valid, unused)
    float xr_n = xq[0], xz_n = xq[NH], xn_n = xq[2 * NH];

    const char* hb = smh + (t & 1) * 576 + c * 144;
    float a0 = 0.f, a1 = 0.f, a2 = 0.f, a3 = 0.f, a4 = 0.f, a5 = 0.f;
    int4 q0 = *(const int4*)(hb +   0), q1 = *(const int4*)(hb +  16);
    int4 q2 = *(const int4*)(hb +  32), q3 = *(const int4*)(hb +  48);
    int4 q4 = *(const int4*)(hb +  64), q5 = *(const int4*)(hb +  80);
    int4 q6 = *(const int4*)(hb +  96), q7 = *(const int4*)(hb + 112);
    DOT6(q0, W0a, W1a, W2a, W3a, W4a, W5a, 0);
    DOT6(q1, W0a, W1a, W2a, W3a, W4a, W5a, 4);
    DOT6(q2, W0a, W1a, W2a, W3a, W4a, W5a, 8);
    DOT6(q3, W0a, W1a, W2a, W3a, W4a, W5a, 12);
    DOT6(q4, W0b, W1b, W2b, W3b, W4b, W5b, 0);
    DOT6(q5, W0b, W1b, W2b, W3b, W4b, W5b, 4);
    DOT6(q6, W0b, W1b, W2b, W3b, W4b, W5b, 8);
    DOT6(q7, W0b, W1b, W2b, W3b, W4b, W5b, 12);

    // 4-way K reduction in-register; every lane gets full sums
    float s0 = quad_sum(a0), s1 = quad_sum(a1);
    float s2 = quad_sum(a2), s3 = quad_sum(a3);
    float s4 = quad_sum(a4), s5 = quad_sum(a5);
    float mvr = jj ? s1 : s0;
    float mvz = jj ? s3 : s2;
    float mvn = jj ? s5 : s4;

    float r = sigmoid_fast(xr_c + mvr);
    float z = sigmoid_fast(xz_c + mvz);
    float n = tanh_fast(xn_c + mvn + r * mvn);  // torch quirk: mv_n enters twice
    h = z * (h - n) + n;

    if (c < 2) {
      op[0] = h;
      *(_Float16*)(smh + (((t + 1) & 1) * 576) + wofs) = (_Float16)h;
    }
    // h ds_write visible to all waves; no vmcnt drain (stores stay in flight)
    asm volatile("s_waitcnt lgkmcnt(0)\n\ts_barrier" ::: "memory");

    xr_c = xr_n; xz_c = xz_n; xn_c = xn_n;
    xq += (size_t)BATCH * NG;
    op += (size_t)BATCH * NH;
  }

  if (c < 2) out[(size_t)S_LEN * BATCH * NH + (size_t)b * NH + jmine] = h;
}

extern "C" void kernel_launch(void* const* d_in, const int* in_sizes, int n_in,
                              void* d_out, int out_size, void* d_ws, size_t ws_size,
                              hipStream_t stream) {
  const float* input = (const float*)d_in[0];
  const float* W_ih  = (const float*)d_in[1];
  const float* W_hh  = (const float*)d_in[2];
  const float* b_ih  = (const float*)d_in[3];
  const float* b_hh  = (const float*)d_in[4];
  float* out = (float*)d_out;

  const size_t SB = (size_t)S_LEN * BATCH;           // 65536
  const size_t xp_b   = SB * NG * 4;                 // 192 MiB
  const size_t in16_b = SB * NIN * 2;                // 32 MiB
  const size_t w_b    = (size_t)128 * NG * 4;        // 384 KiB each

  char* p = (char*)d_ws;
  float*    xp    = (float*)p;                p += xp_b;
  _Float16* in16  = (_Float16*)p;             p += in16_b;
  half2_t*  whh3  = (half2_t*)p;              p += w_b;
  half2_t*  wih2  = (half2_t*)p;              p += w_b;
  float*    bias  = (float*)p;

  prep_in_kernel<<<8192, 256, 0, stream>>>(input, in16);
  prep_w_kernel<<<(2 * 128 * NG + NG + 255) / 256, 256, 0, stream>>>(W_ih, W_hh, b_ih, b_hh,
                                                                     whh3, wih2, bias);
  xproj_kernel<<<1024, 768, 0, stream>>>(in16, wih2, bias, xp);
  gru_kernel<<<BATCH, 512, 0, stream>>>(xp, whh3, out);
  (void)out_size; (void)n_in; (void)in_sizes; (void)ws_size;
}